// Round 2
// 474.097 us; speedup vs baseline: 1.0404x; 1.0404x over previous
//
#include <hip/hip_runtime.h>
#include <cmath>

#ifndef M_PI
#define M_PI 3.14159265358979323846
#endif

#define NS 7          // NUM_SPHERICAL
#define NR 6          // NUM_RADIAL
#define NSPH 49       // NS*NS
#define NRB 42        // NS*NR
#define NOUT 294      // NSPH*NR
#define QPB 64        // quads per block
#define NTHREADS 512
#define RBF_PAD 44
#define SPH_PAD 50

// native clang vector type: __builtin_nontemporal_store requires it
typedef float vfloat4 __attribute__((ext_vector_type(4)));

struct Consts {
  float zb[NS][NR];   // Bessel zeros Z[l][j]
  float bn[NS][NR];   // BNORM[l][j] * norm_const
  float kc[NS][NS];   // (m==0 ? 1 : sqrt2) * K(l,m)
};

// ---------------- host-side constant generation (mirrors reference, f64) ----
static double sph_jn_d(int n, double x) {
  double j0 = sin(x) / x;
  if (n == 0) return j0;
  double j1 = sin(x) / (x * x) - cos(x) / x;
  double jm1 = j0, jc = j1;
  for (int l = 1; l < n; ++l) {
    double nx = (2.0 * l + 1.0) / x * jc - jm1;
    jm1 = jc; jc = nx;
  }
  return jc;
}

static Consts make_consts() {
  Consts C;
  double zeros[NS][NR];
  double points[NS + NR];
  for (int j = 0; j < NR; ++j) zeros[0][j] = (j + 1) * M_PI;
  for (int i = 0; i < NS + NR - 1; ++i) points[i] = (i + 1) * M_PI;
  for (int order = 1; order < NS; ++order) {
    int nroots = NR + NS - 1 - order;
    double racines[NS + NR];
    for (int j = 0; j < nroots; ++j) {
      double a = points[j], b = points[j + 1];
      double fa = sph_jn_d(order, a);
      for (int it = 0; it < 80; ++it) {
        double m = 0.5 * (a + b);
        double fm = sph_jn_d(order, m);
        if (fa * fm <= 0.0) b = m;
        else { a = m; fa = fm; }
      }
      racines[j] = 0.5 * (a + b);
    }
    for (int j = 0; j < nroots; ++j) points[j] = racines[j];
    for (int j = 0; j < NR; ++j) zeros[order][j] = racines[j];
  }
  const double norm_const = pow(1.0 / 5.0, 1.5);  // inv_cutoff^1.5
  for (int l = 0; l < NS; ++l)
    for (int j = 0; j < NR; ++j) {
      C.zb[l][j] = (float)zeros[l][j];
      double jn1 = sph_jn_d(l + 1, zeros[l][j]);
      C.bn[l][j] = (float)(1.0 / sqrt(0.5 * jn1 * jn1) * norm_const);
    }
  double fact[16]; fact[0] = 1.0;
  for (int i = 1; i < 16; ++i) fact[i] = fact[i - 1] * i;
  for (int l = 0; l < NS; ++l)
    for (int m = 0; m < NS; ++m) {
      if (m > l) { C.kc[l][m] = 0.f; continue; }
      double K = sqrt((2.0 * l + 1.0) / (4.0 * M_PI) * fact[l - m] / fact[l + m]);
      C.kc[l][m] = (float)((m == 0) ? K : sqrt(2.0) * K);
    }
  return C;
}

// ---------------- kernel -----------------------------------------------------
// Role split is WAVE-ALIGNED to avoid intra-wave path serialization:
//   wave 0  (tid   0.. 63): spherical harmonics for all 64 quads, BEFORE barrier 1
//                           (overlaps the id4->D gather latency issued by wave 1)
//   tid  64..127          : id4->D gather + envelope u(d)        (phase 0)
//   tid 128..511          : build index table + copy consts      (phase 0)
//   tid  64..511 (7 waves): 6 Bessel tasks each (448*6 = 64*42)  (phase 2)
//   all 512               : unrolled float4 nontemporal store    (phase 3)
__global__ __launch_bounds__(NTHREADS, 4)
void tensor_basis_kernel(const float* __restrict__ D,
                         const float* __restrict__ Alpha,
                         const float* __restrict__ Theta,
                         const int* __restrict__ id4,
                         float* __restrict__ out,
                         int nq, Consts C) {
  __shared__ float s_d[QPB], s_u[QPB];
  __shared__ float s_rbf[QPB][RBF_PAD];
  __shared__ float s_sph[QPB][SPH_PAD];
  __shared__ unsigned short s_tab[NOUT];
  __shared__ float s_zb[NRB], s_bn[NRB];

  const int tid = threadIdx.x;
  const int q0 = blockIdx.x * QPB;

  if (tid < QPB) {
    // ---- spherical harmonics: one full wave, one quad per lane, pre-barrier
    int q = q0 + tid;
    float alpha = 0.f, theta = 0.f;
    if (q < nq) { alpha = Alpha[q]; theta = Theta[q]; }
    float st, ct; sincosf(alpha, &st, &ct);
    float sp, cp; sincosf(theta, &sp, &cp);
    float P[NS][NS];
    P[0][0] = 1.f;
#pragma unroll
    for (int m = 0; m < NS; ++m) {
      if (m > 0) P[m][m] = (1.f - 2.f * (float)m) * st * P[m - 1][m - 1];
      if (m + 1 < NS) P[m + 1][m] = (2.f * (float)m + 1.f) * ct * P[m][m];
#pragma unroll
      for (int l = m + 2; l < NS; ++l)
        P[l][m] = ((2.f * (float)l - 1.f) * ct * P[l - 1][m] -
                   (float)(l + m - 1) * P[l - 2][m]) / (float)(l - m);
    }
    float cm[NS], sm[NS];
    cm[0] = 1.f; sm[0] = 0.f;
    cm[1] = cp;  sm[1] = sp;
#pragma unroll
    for (int m = 2; m < NS; ++m) {
      cm[m] = 2.f * cp * cm[m - 1] - cm[m - 2];
      sm[m] = 2.f * cp * sm[m - 1] - sm[m - 2];
    }
    int idx = 0;
#pragma unroll
    for (int l = 0; l < NS; ++l) {
      s_sph[tid][idx++] = C.kc[l][0] * P[l][0];
#pragma unroll
      for (int m = 1; m <= l; ++m)
        s_sph[tid][idx++] = C.kc[l][m] * cm[m] * P[l][m];
#pragma unroll
      for (int m = l; m >= 1; --m)
        s_sph[tid][idx++] = C.kc[l][m] * sm[m] * P[l][m];
    }
  } else if (tid < 2 * QPB) {
    // ---- d + envelope u(d): dependent gather id4 -> D, issued ASAP
    int lq = tid - QPB;
    int q = q0 + lq;
    float d = 0.5f, u = 0.f;
    if (q < nq) {
      int e = id4[q];
      d = D[e] * 0.2f;  // * inv_cutoff
      float d2 = d * d, d4 = d2 * d2, d5 = d4 * d;
      // p=6: 1/d - 28 d^5 + 48 d^6 - 21 d^7
      u = (d < 1.f) ? (1.f / d + d5 * (-28.f + d * (48.f - 21.f * d))) : 0.f;
    }
    s_d[lq] = d;
    s_u[lq] = u;
  } else {
    // ---- index table + consts, spread across threads (no serial tid==0 chain)
    int t = tid - 2 * QPB;               // 0..383
    if (t < NOUT) {
      int s = t / NR;
      int j = t - NR * s;
      int l = (int)sqrtf((float)s + 0.5f);  // L_INDEX: l = floor(sqrt(s))
      s_tab[t] = (unsigned short)((s << 8) | (l * NR + j));
    } else if (t < NOUT + NRB) {
      int u2 = t - NOUT;
      s_zb[u2] = ((const float*)C.zb)[u2];  // kernarg, flat-indexed loads
      s_bn[u2] = ((const float*)C.bn)[u2];
    }
  }
  __syncthreads();

  // --- Phase 2: radial Bessel basis, 7 full waves, 6 tasks each --------------
  if (tid >= QPB) {
    int t = tid - QPB;  // 0..447 ; 448 threads * 6 tasks = 64*42 exactly
#pragma unroll
    for (int k = 0; k < 6; ++k) {
      int task = t + k * 448;
      int ql = task / NRB;
      int idx = task - ql * NRB;
      int l = idx / NR;
      float d = s_d[ql];
      float x = d * s_zb[idx];
      float sx, cx; sincosf(x, &sx, &cx);
      float invx = 1.f / x;
      float jl = sx * invx;                     // j0
      if (l > 0) {
        float jm1 = jl;
        float jc = sx * invx * invx - cx * invx;  // j1 (matches reference)
        for (int ll = 1; ll < l; ++ll) {
          float nx = (2.f * (float)ll + 1.f) * invx * jc - jm1;
          jm1 = jc; jc = nx;
        }
        jl = jc;
      }
      s_rbf[ql][idx] = s_u[ql] * s_bn[idx] * jl;
    }
  }
  __syncthreads();

  // --- Phase 3: coalesced float4 nontemporal stores of 64*294 = 18816 floats -
  const int ebase = q0 * NOUT;
  const int tot = nq * NOUT;
  auto do4 = [&](int f) {
    int e = 4 * f;
    int ql = e / NOUT;
    int i0 = e - ql * NOUT;
    float v[4];
#pragma unroll
    for (int c = 0; c < 4; ++c) {
      int ii = i0 + c, qq = ql;
      if (ii >= NOUT) { ii -= NOUT; ++qq; }  // 294 % 4 != 0: may cross quad row
      unsigned t2 = s_tab[ii];
      v[c] = s_rbf[qq][t2 & 0xFFu] * s_sph[qq][t2 >> 8];
    }
    int g = ebase + e;
    if (g + 3 < tot) {
      vfloat4 pv; pv.x = v[0]; pv.y = v[1]; pv.z = v[2]; pv.w = v[3];
      __builtin_nontemporal_store(pv, reinterpret_cast<vfloat4*>(out + g));
    } else {
#pragma unroll
      for (int c = 0; c < 4; ++c)
        if (g + c < tot) out[g + c] = v[c];
    }
  };
  // (QPB*NOUT)/4 = 4704 = 9*512 + 96: 9 guaranteed iterations + partial tail.
#pragma unroll 3
  for (int it = 0; it < 9; ++it) do4(tid + it * NTHREADS);
  {
    int f = tid + 9 * NTHREADS;
    if (f < (QPB * NOUT) / 4) do4(f);
  }
}

// ---------------- launch -----------------------------------------------------
extern "C" void kernel_launch(void* const* d_in, const int* in_sizes, int n_in,
                              void* d_out, int out_size, void* d_ws, size_t ws_size,
                              hipStream_t stream) {
  (void)n_in; (void)out_size; (void)d_ws; (void)ws_size;
  static const Consts C = make_consts();   // host-only, computed once
  const float* D     = (const float*)d_in[0];
  const float* Alpha = (const float*)d_in[1];
  const float* Theta = (const float*)d_in[2];
  const int*   id4   = (const int*)d_in[3];
  // d_in[4] (Kidx) is unused by the reference
  float* out = (float*)d_out;
  const int nq = in_sizes[1];
  const int blocks = (nq + QPB - 1) / QPB;
  hipLaunchKernelGGL(tensor_basis_kernel, dim3(blocks), dim3(NTHREADS), 0, stream,
                     D, Alpha, Theta, id4, out, nq, C);
}